// Round 2
// baseline (1485.877 us; speedup 1.0000x reference)
//
#include <hip/hip_runtime.h>
#include <cstddef>
#include <cstdint>

using ushort = unsigned short;
using short8 = __attribute__((ext_vector_type(8))) short;
using f32x4  = __attribute__((ext_vector_type(4))) float;
using u16x4  = __attribute__((ext_vector_type(4))) ushort;

#define L_DIM 1024
#define B_DIM 32
#define D_DIM 1024
#define N_DIM 3072    // 3*D
#define K_DIM 1024    // D
#define BD    (B_DIM * D_DIM)      // 32768 chains
#define HB    ((size_t)L_DIM * BD) // h element count

// ---------- bf16 helpers (RNE) ----------
__device__ __forceinline__ ushort f2bf(float f) {
  unsigned u = __builtin_bit_cast(unsigned, f);
  u += 0x7fffu + ((u >> 16) & 1u);
  return (ushort)(u >> 16);
}
__device__ __forceinline__ float bf2f(ushort s) {
  return __builtin_bit_cast(float, (unsigned)s << 16);
}

// ---------- prepass: split an x-chunk into bf16 hi/lo planes ----------
__global__ void prep_x(const float* __restrict__ x,
                       ushort* __restrict__ xhi, ushort* __restrict__ xlo) {
  size_t i = (size_t)blockIdx.x * 256 + threadIdx.x;   // one float4 per thread
  f32x4 v = ((const f32x4*)x)[i];
  u16x4 h, l;
#pragma unroll
  for (int j = 0; j < 4; ++j) {
    ushort hb = f2bf(v[j]);
    float lof = v[j] - bf2f(hb);
    h[j] = hb;
    l[j] = f2bf(lof);
  }
  ((u16x4*)xhi)[i] = h;
  ((u16x4*)xlo)[i] = l;
}

// ---------- prepass: transpose W (K x N) -> Wt (N x K), split hi/lo ----------
__global__ void prep_w(const float* __restrict__ W,
                       ushort* __restrict__ wthi, ushort* __restrict__ wtlo) {
  __shared__ float tile[32][33];
  const int c0 = blockIdx.x * 32;   // N
  const int r0 = blockIdx.y * 32;   // K
  const int tx = threadIdx.x & 31, ty = threadIdx.x >> 5;  // ty 0..7
#pragma unroll
  for (int i = 0; i < 4; ++i)
    tile[ty + 8 * i][tx] = W[(size_t)(r0 + ty + 8 * i) * N_DIM + c0 + tx];
  __syncthreads();
#pragma unroll
  for (int i = 0; i < 4; ++i) {
    int cc = ty + 8 * i;
    float v = tile[tx][cc];          // W[r0+tx][c0+cc]
    ushort hb = f2bf(v);
    float lof = v - bf2f(hb);
    size_t o = (size_t)(c0 + cc) * K_DIM + r0 + tx;
    wthi[o] = hb;
    wtlo[o] = f2bf(lof);
  }
}

// ---------- GEMM (per L-chunk): u[Mc x N] = 3-segment bf16 product ----------
// segments: xhi*Whi + xhi*Wlo + xlo*Whi  (fp32 split into bf16 hi+lo)
// 128x128 tile, BK=64, 4 waves (2x2), 4x4 16x16x32 frags/wave.
// LDS [128][64] bf16, XOR swizzle byte^=((row&7)<<4) via pre-swizzled
// GLOBAL source (global_load_lds dest must be lane-linear).
__global__ __launch_bounds__(256, 3)
void gemm_kernel(const ushort* __restrict__ xhi, const ushort* __restrict__ xlo,
                 const ushort* __restrict__ wthi, const ushort* __restrict__ wtlo,
                 float* __restrict__ u) {
  __shared__ __align__(16) ushort As[128 * 64];
  __shared__ __align__(16) ushort Bs[128 * 64];

  const int m0 = blockIdx.y * 128;   // chunk-local row
  const int n0 = blockIdx.x * 128;
  const int t = threadIdx.x;
  const int lane = t & 63;
  const int wid = t >> 6;
  const int wr = (wid >> 1) * 64;
  const int wc = (wid & 1) * 64;

  f32x4 acc[4][4];
#pragma unroll
  for (int i = 0; i < 4; ++i)
#pragma unroll
    for (int j = 0; j < 4; ++j)
      acc[i][j] = (f32x4){0.f, 0.f, 0.f, 0.f};

  // staging: thread t covers 16B at linear LDS byte i*4096 + t*16
  const int srow = t >> 3;                 // 0..31 (+i*32 per issue)
  const int sc   = (t & 7) * 16;
  const int swz  = sc ^ ((srow & 7) << 4); // pre-swizzled source byte col
  const int kcol = swz >> 1;
  const int ldsoff = srow * 128 + sc;

  for (int kt = 0; kt < 48; ++kt) {
    const int seg = kt >> 4;
    const int ko = (kt & 15) * 64;
    const ushort* Aseg = (seg < 2) ? xhi : xlo;
    const ushort* Bseg = (seg == 1) ? wtlo : wthi;

#pragma unroll
    for (int i = 0; i < 4; ++i) {
      const ushort* src = Aseg + (size_t)(m0 + i * 32 + srow) * K_DIM + ko + kcol;
      __builtin_amdgcn_global_load_lds(
          (__attribute__((address_space(1))) void*)(void*)src,
          (__attribute__((address_space(3))) void*)((char*)As + i * 4096 + ldsoff),
          16, 0, 0);
    }
#pragma unroll
    for (int i = 0; i < 4; ++i) {
      const ushort* src = Bseg + (size_t)(n0 + i * 32 + srow) * K_DIM + ko + kcol;
      __builtin_amdgcn_global_load_lds(
          (__attribute__((address_space(1))) void*)(void*)src,
          (__attribute__((address_space(3))) void*)((char*)Bs + i * 4096 + ldsoff),
          16, 0, 0);
    }
    __syncthreads();

#pragma unroll
    for (int kk = 0; kk < 2; ++kk) {
      short8 a[4], b[4];
      const int k0b = kk * 64 + ((lane >> 4) << 4);
#pragma unroll
      for (int mi = 0; mi < 4; ++mi) {
        int row = wr + mi * 16 + (lane & 15);
        int byte = row * 128 + (k0b ^ ((row & 7) << 4));
        a[mi] = *(const short8*)((const char*)As + byte);
      }
#pragma unroll
      for (int ni = 0; ni < 4; ++ni) {
        int row = wc + ni * 16 + (lane & 15);
        int byte = row * 128 + (k0b ^ ((row & 7) << 4));
        b[ni] = *(const short8*)((const char*)Bs + byte);
      }
#pragma unroll
      for (int mi = 0; mi < 4; ++mi)
#pragma unroll
        for (int ni = 0; ni < 4; ++ni)
          acc[mi][ni] = __builtin_amdgcn_mfma_f32_16x16x32_bf16(
              a[mi], b[ni], acc[mi][ni], 0, 0, 0);
    }
    __syncthreads();
  }

  // epilogue: C/D layout col=lane&15, row=(lane>>4)*4+r
  const int lr = (lane >> 4) << 2;
  const int lc = lane & 15;
#pragma unroll
  for (int mi = 0; mi < 4; ++mi)
#pragma unroll
    for (int ni = 0; ni < 4; ++ni)
#pragma unroll
      for (int r = 0; r < 4; ++r) {
        int row = wr + mi * 16 + lr + r;
        int col = wc + ni * 16 + lc;
        u[(size_t)(m0 + row) * N_DIM + (n0 + col)] = acc[mi][ni][r];
      }
}

// ---------- scan over one L-chunk, one thread per (b,d) chain ----------
__global__ __launch_bounds__(256)
void scan_kernel(const float* __restrict__ u,       // chunk-local (LC*B x 3072)
                 const float* __restrict__ x,       // full x
                 const float* __restrict__ bias,
                 const float* __restrict__ cin,     // c0 (chunk 0) or c_state
                 const int* __restrict__ lens,
                 float* __restrict__ h_out,         // full h
                 float* __restrict__ c_state,
                 float* __restrict__ final_dst,     // == c_state except last chunk
                 int t0, int LC) {
  const int tid = blockIdx.x * 256 + threadIdx.x;   // 0..32767
  const int b = tid >> 10;
  const int d = tid & 1023;
  const int len = lens[b];
  const float bf = bias[d];
  const float br = bias[D_DIM + d];
  float c = cin[tid];

  constexpr int PF = 8;
  float pu0[PF], pu1[PF], pu2[PF], px[PF];
#pragma unroll
  for (int j = 0; j < PF; ++j) {
    size_t ml = (size_t)j * B_DIM + b;
    const float* up = u + ml * N_DIM + 3 * d;
    pu0[j] = up[0]; pu1[j] = up[1]; pu2[j] = up[2];
    px[j] = x[((size_t)(t0 + j) * B_DIM + b) * D_DIM + d];
  }

  for (int tb = 0; tb < LC; tb += PF) {
    const bool more = (tb < LC - PF);
#pragma unroll
    for (int j = 0; j < PF; ++j) {
      const int tl = tb + j;                 // chunk-local t
      float u0 = pu0[j], z1 = pu1[j] + bf, z2 = pu2[j] + br, xt = px[j];
      if (more) {
        size_t ml = (size_t)(tl + PF) * B_DIM + b;
        const float* up = u + ml * N_DIM + 3 * d;
        pu0[j] = up[0]; pu1[j] = up[1]; pu2[j] = up[2];
        px[j] = x[((size_t)(t0 + tl + PF) * B_DIM + b) * D_DIM + d];
      }
      float g1 = 1.0f / (1.0f + __expf(-z1));
      float g2 = 1.0f / (1.0f + __expf(-z2));
      float cn = (c - u0) * g1 + u0;
      float th = 1.0f - 2.0f / (1.0f + __expf(2.0f * cn));
      float h = (th - xt) * g2 + xt;
      bool valid = (t0 + tl) < len;
      c = valid ? cn : c;
      h_out[(size_t)(t0 + tl) * BD + tid] = valid ? h : 0.0f;
    }
  }
  c_state[tid] = c;
  final_dst[tid] = c;
}

extern "C" void kernel_launch(void* const* d_in, const int* in_sizes, int n_in,
                              void* d_out, int out_size, void* d_ws, size_t ws_size,
                              hipStream_t stream) {
  const float* x    = (const float*)d_in[0];
  const float* W    = (const float*)d_in[1];
  const float* bias = (const float*)d_in[2];
  const float* c0   = (const float*)d_in[3];
  const int*   lens = (const int*)d_in[4];
  float* out = (float*)d_out;
  float* cell_out = out + HB;

  // ---- workspace layout (adaptive chunk size LC) ----
  // fixed: wthi(6291456) + wtlo(6291456) + c_state(131072) = 12,713,984 B
  // per-chunk: xhi,xlo (LC*65536 each) + u (LC*393216)  => LC*524288 B
  char* ws = (char*)d_ws;
  ushort* wthi = (ushort*)ws;
  ushort* wtlo = (ushort*)(ws + 6291456ull);
  float*  c_state = (float*)(ws + 12582912ull);
  const size_t fixed = 12713984ull;

  int LC = 8;
  {
    const int cands[6] = {1024, 512, 256, 128, 64, 32};
    for (int i = 0; i < 6; ++i)
      if (fixed + (size_t)cands[i] * 524288ull <= ws_size) { LC = cands[i]; break; }
  }
  ushort* xhi = (ushort*)(ws + fixed);
  ushort* xlo = xhi + (size_t)LC * B_DIM * D_DIM;
  float*  u   = (float*)(xlo + (size_t)LC * B_DIM * D_DIM);

  prep_w<<<dim3(96, 32), dim3(256), 0, stream>>>(W, wthi, wtlo);

  const int NC = L_DIM / LC;
  for (int ci = 0; ci < NC; ++ci) {
    const int t0 = ci * LC;
    const float* xc = x + (size_t)t0 * B_DIM * D_DIM;
    const int nfl4 = LC * B_DIM * D_DIM / 4;           // float4s in chunk
    prep_x<<<dim3(nfl4 / 256), dim3(256), 0, stream>>>(xc, xhi, xlo);
    gemm_kernel<<<dim3(24, LC * B_DIM / 128), dim3(256), 0, stream>>>(
        xhi, xlo, wthi, wtlo, u);
    const float* cin = (ci == 0) ? c0 : c_state;
    float* fdst = (ci == NC - 1) ? cell_out : c_state;
    scan_kernel<<<dim3(BD / 256), dim3(256), 0, stream>>>(
        u, x, bias, cin, lens, out, c_state, fdst, t0, LC);
  }
}

// Round 3
// 953.784 us; speedup vs baseline: 1.5579x; 1.5579x over previous
//
#include <hip/hip_runtime.h>
#include <cstddef>
#include <cstdint>

using ushort = unsigned short;
using short8 = __attribute__((ext_vector_type(8))) short;
using f32x4  = __attribute__((ext_vector_type(4))) float;
using u16x4  = __attribute__((ext_vector_type(4))) ushort;

#define L_DIM 1024
#define B_DIM 32
#define D_DIM 1024
#define N_DIM 3072    // 3*D
#define K_DIM 1024    // D
#define BD    (B_DIM * D_DIM)      // 32768 chains
#define HB    ((size_t)L_DIM * BD) // h element count
#define TSTRIDE (B_DIM * N_DIM)    // floats per timestep in u (plane-ordered)

// ---------- bf16 helpers (RNE) ----------
__device__ __forceinline__ ushort f2bf(float f) {
  unsigned u = __builtin_bit_cast(unsigned, f);
  u += 0x7fffu + ((u >> 16) & 1u);
  return (ushort)(u >> 16);
}
__device__ __forceinline__ float bf2f(ushort s) {
  return __builtin_bit_cast(float, (unsigned)s << 16);
}

// ---------- prepass: split an x-chunk into bf16 hi/lo planes ----------
__global__ void prep_x(const float* __restrict__ x,
                       ushort* __restrict__ xhi, ushort* __restrict__ xlo) {
  size_t i = (size_t)blockIdx.x * 256 + threadIdx.x;   // one float4 per thread
  f32x4 v = ((const f32x4*)x)[i];
  u16x4 h, l;
#pragma unroll
  for (int j = 0; j < 4; ++j) {
    ushort hb = f2bf(v[j]);
    float lof = v[j] - bf2f(hb);
    h[j] = hb;
    l[j] = f2bf(lof);
  }
  ((u16x4*)xhi)[i] = h;
  ((u16x4*)xlo)[i] = l;
}

// ---------- prepass: transpose W (K x N) -> Wt (N' x K), split hi/lo ----------
// Column permutation n' = (c%3)*1024 + c/3 so u comes out PLANE-ordered:
// u[m][plane][d] with plane 0=u0, 1=gate_f pre-act, 2=gate_r pre-act.
__global__ void prep_w(const float* __restrict__ W,
                       ushort* __restrict__ wthi, ushort* __restrict__ wtlo) {
  __shared__ float tile[32][33];
  const int c0 = blockIdx.x * 32;   // N
  const int r0 = blockIdx.y * 32;   // K
  const int tx = threadIdx.x & 31, ty = threadIdx.x >> 5;  // ty 0..7
#pragma unroll
  for (int i = 0; i < 4; ++i)
    tile[ty + 8 * i][tx] = W[(size_t)(r0 + ty + 8 * i) * N_DIM + c0 + tx];
  __syncthreads();
#pragma unroll
  for (int i = 0; i < 4; ++i) {
    int cc = ty + 8 * i;
    int c = c0 + cc;
    int np = (c % 3) * D_DIM + c / 3;    // permuted column
    float v = tile[tx][cc];              // W[r0+tx][c]
    ushort hb = f2bf(v);
    float lof = v - bf2f(hb);
    size_t o = (size_t)np * K_DIM + r0 + tx;
    wthi[o] = hb;
    wtlo[o] = f2bf(lof);
  }
}

// ---------- GEMM (per L-chunk): u[Mc x N'] = 3-segment bf16 product ----------
// segments: xhi*Whi + xhi*Wlo + xlo*Whi  (fp32 split into bf16 hi+lo)
// 128x128 tile, BK=64, 4 waves (2x2), 4x4 16x16x32 frags/wave.
// LDS [128][64] bf16, XOR swizzle byte^=((row&7)<<4) via pre-swizzled
// GLOBAL source (global_load_lds dest must be lane-linear).
__global__ __launch_bounds__(256, 3)
void gemm_kernel(const ushort* __restrict__ xhi, const ushort* __restrict__ xlo,
                 const ushort* __restrict__ wthi, const ushort* __restrict__ wtlo,
                 float* __restrict__ u) {
  __shared__ __align__(16) ushort As[128 * 64];
  __shared__ __align__(16) ushort Bs[128 * 64];

  const int m0 = blockIdx.y * 128;   // chunk-local row
  const int n0 = blockIdx.x * 128;
  const int t = threadIdx.x;
  const int lane = t & 63;
  const int wid = t >> 6;
  const int wr = (wid >> 1) * 64;
  const int wc = (wid & 1) * 64;

  f32x4 acc[4][4];
#pragma unroll
  for (int i = 0; i < 4; ++i)
#pragma unroll
    for (int j = 0; j < 4; ++j)
      acc[i][j] = (f32x4){0.f, 0.f, 0.f, 0.f};

  const int srow = t >> 3;                 // 0..31 (+i*32 per issue)
  const int sc   = (t & 7) * 16;
  const int swz  = sc ^ ((srow & 7) << 4); // pre-swizzled source byte col
  const int kcol = swz >> 1;
  const int ldsoff = srow * 128 + sc;

  for (int kt = 0; kt < 48; ++kt) {
    const int seg = kt >> 4;
    const int ko = (kt & 15) * 64;
    const ushort* Aseg = (seg < 2) ? xhi : xlo;
    const ushort* Bseg = (seg == 1) ? wtlo : wthi;

#pragma unroll
    for (int i = 0; i < 4; ++i) {
      const ushort* src = Aseg + (size_t)(m0 + i * 32 + srow) * K_DIM + ko + kcol;
      __builtin_amdgcn_global_load_lds(
          (__attribute__((address_space(1))) void*)(void*)src,
          (__attribute__((address_space(3))) void*)((char*)As + i * 4096 + ldsoff),
          16, 0, 0);
    }
#pragma unroll
    for (int i = 0; i < 4; ++i) {
      const ushort* src = Bseg + (size_t)(n0 + i * 32 + srow) * K_DIM + ko + kcol;
      __builtin_amdgcn_global_load_lds(
          (__attribute__((address_space(1))) void*)(void*)src,
          (__attribute__((address_space(3))) void*)((char*)Bs + i * 4096 + ldsoff),
          16, 0, 0);
    }
    __syncthreads();

#pragma unroll
    for (int kk = 0; kk < 2; ++kk) {
      short8 a[4], b[4];
      const int k0b = kk * 64 + ((lane >> 4) << 4);
#pragma unroll
      for (int mi = 0; mi < 4; ++mi) {
        int row = wr + mi * 16 + (lane & 15);
        int byte = row * 128 + (k0b ^ ((row & 7) << 4));
        a[mi] = *(const short8*)((const char*)As + byte);
      }
#pragma unroll
      for (int ni = 0; ni < 4; ++ni) {
        int row = wc + ni * 16 + (lane & 15);
        int byte = row * 128 + (k0b ^ ((row & 7) << 4));
        b[ni] = *(const short8*)((const char*)Bs + byte);
      }
#pragma unroll
      for (int mi = 0; mi < 4; ++mi)
#pragma unroll
        for (int ni = 0; ni < 4; ++ni)
          acc[mi][ni] = __builtin_amdgcn_mfma_f32_16x16x32_bf16(
              a[mi], b[ni], acc[mi][ni], 0, 0, 0);
    }
    __syncthreads();
  }

  const int lr = (lane >> 4) << 2;
  const int lc = lane & 15;
#pragma unroll
  for (int mi = 0; mi < 4; ++mi)
#pragma unroll
    for (int ni = 0; ni < 4; ++ni)
#pragma unroll
      for (int r = 0; r < 4; ++r) {
        int row = wr + mi * 16 + lr + r;
        int col = wc + ni * 16 + lc;
        u[(size_t)(m0 + row) * N_DIM + (n0 + col)] = acc[mi][ni][r];
      }
}

// ---------- parallel scan over L (linear recurrence c_t = a_t*c + b_t) ----------
// pass A: per (chain, sub-chunk of 32 t): compose (A,B). reads u0,u1 planes.
__global__ __launch_bounds__(256)
void scanA(const float* __restrict__ u, const float* __restrict__ bias,
           const int* __restrict__ lens,
           float* __restrict__ Asum, float* __restrict__ Bsum, int t0) {
  const int tid = blockIdx.x * 256 + threadIdx.x;   // chain
  const int s = blockIdx.y;                         // sub-chunk
  const int b = tid >> 10, d = tid & 1023;
  const int len = lens[b];
  const float bf = bias[d];
  const size_t off = (size_t)b * N_DIM + d;         // plane-ordered base
  float A = 1.f, Bc = 0.f;

  constexpr int PF = 8;
  float p0[PF], p1[PF];
#pragma unroll
  for (int j = 0; j < PF; ++j) {
    size_t o = (size_t)(s * 32 + j) * TSTRIDE + off;
    p0[j] = u[o];
    p1[j] = u[o + D_DIM];
  }
  for (int tb = 0; tb < 32; tb += PF) {
    const bool more = tb + PF < 32;
#pragma unroll
    for (int j = 0; j < PF; ++j) {
      const int tl = s * 32 + tb + j;
      float u0 = p0[j], u1 = p1[j];
      if (more) {
        size_t o = (size_t)(tl + PF) * TSTRIDE + off;
        p0[j] = u[o];
        p1[j] = u[o + D_DIM];
      }
      float g1 = 1.0f / (1.0f + __expf(-(u1 + bf)));
      bool valid = (t0 + tl) < len;
      float a = valid ? g1 : 1.0f;
      float bb = valid ? (1.0f - g1) * u0 : 0.0f;
      A = a * A;
      Bc = a * Bc + bb;
    }
  }
  Asum[(size_t)s * BD + tid] = A;
  Bsum[(size_t)s * BD + tid] = Bc;
}

// pass B: sequential over NSUB sub-chunk summaries; emits incoming c per sub-chunk.
__global__ __launch_bounds__(256)
void scanB(const float* __restrict__ Asum, const float* __restrict__ Bsum,
           const float* __restrict__ cin, float* __restrict__ csin,
           float* __restrict__ c_state, float* __restrict__ final_dst, int NSUB) {
  const int tid = blockIdx.x * 256 + threadIdx.x;
  float c = cin[tid];
  for (int s = 0; s < NSUB; ++s) {
    csin[(size_t)s * BD + tid] = c;
    c = Asum[(size_t)s * BD + tid] * c + Bsum[(size_t)s * BD + tid];
  }
  c_state[tid] = c;
  final_dst[tid] = c;
}

// pass C: recompute recurrence per sub-chunk from incoming c; emit h.
__global__ __launch_bounds__(256)
void scanC(const float* __restrict__ u, const float* __restrict__ x,
           const float* __restrict__ bias, const float* __restrict__ csin,
           const int* __restrict__ lens, float* __restrict__ h_out, int t0) {
  const int tid = blockIdx.x * 256 + threadIdx.x;
  const int s = blockIdx.y;
  const int b = tid >> 10, d = tid & 1023;
  const int len = lens[b];
  const float bf = bias[d];
  const float br = bias[D_DIM + d];
  const size_t off = (size_t)b * N_DIM + d;
  const size_t xoff = (size_t)b * D_DIM + d;
  float c = csin[(size_t)s * BD + tid];

  constexpr int PF = 4;
  float p0[PF], p1[PF], p2[PF], px[PF];
#pragma unroll
  for (int j = 0; j < PF; ++j) {
    int tl = s * 32 + j;
    size_t o = (size_t)tl * TSTRIDE + off;
    p0[j] = u[o];
    p1[j] = u[o + D_DIM];
    p2[j] = u[o + 2 * D_DIM];
    px[j] = x[(size_t)(t0 + tl) * (B_DIM * D_DIM) + xoff];
  }
  for (int tb = 0; tb < 32; tb += PF) {
    const bool more = tb + PF < 32;
#pragma unroll
    for (int j = 0; j < PF; ++j) {
      const int tl = s * 32 + tb + j;
      float u0 = p0[j], z1 = p1[j] + bf, z2 = p2[j] + br, xt = px[j];
      if (more) {
        size_t o = (size_t)(tl + PF) * TSTRIDE + off;
        p0[j] = u[o];
        p1[j] = u[o + D_DIM];
        p2[j] = u[o + 2 * D_DIM];
        px[j] = x[(size_t)(t0 + tl + PF) * (B_DIM * D_DIM) + xoff];
      }
      float g1 = 1.0f / (1.0f + __expf(-z1));
      float g2 = 1.0f / (1.0f + __expf(-z2));
      float cn = (c - u0) * g1 + u0;
      float th = 1.0f - 2.0f / (1.0f + __expf(2.0f * cn));
      float h = (th - xt) * g2 + xt;
      bool valid = (t0 + tl) < len;
      c = valid ? cn : c;
      h_out[(size_t)(t0 + tl) * BD + tid] = valid ? h : 0.0f;
    }
  }
}

extern "C" void kernel_launch(void* const* d_in, const int* in_sizes, int n_in,
                              void* d_out, int out_size, void* d_ws, size_t ws_size,
                              hipStream_t stream) {
  const float* x    = (const float*)d_in[0];
  const float* W    = (const float*)d_in[1];
  const float* bias = (const float*)d_in[2];
  const float* c0   = (const float*)d_in[3];
  const int*   lens = (const int*)d_in[4];
  float* out = (float*)d_out;
  float* cell_out = out + HB;

  // ---- workspace layout ----
  // fixed: wthi 6291456 | wtlo 6291456 | c_state 131072 |
  //        Asum 4194304 | Bsum 4194304 | csin 4194304   (NSUB_MAX=32)
  char* ws = (char*)d_ws;
  ushort* wthi = (ushort*)ws;
  ushort* wtlo = (ushort*)(ws + 6291456ull);
  float*  c_state = (float*)(ws + 12582912ull);
  float*  Asum = (float*)(ws + 12713984ull);
  float*  Bsum = (float*)(ws + 16908288ull);
  float*  csin = (float*)(ws + 21102592ull);
  const size_t fixed = 25296896ull;

  int LC = 32;
  {
    const int cands[6] = {1024, 512, 256, 128, 64, 32};
    for (int i = 0; i < 6; ++i)
      if (fixed + (size_t)cands[i] * 524288ull <= ws_size) { LC = cands[i]; break; }
  }
  ushort* xhi = (ushort*)(ws + fixed);
  ushort* xlo = xhi + (size_t)LC * B_DIM * D_DIM;
  float*  u   = (float*)(xlo + (size_t)LC * B_DIM * D_DIM);
  const int NSUB = LC / 32;

  prep_w<<<dim3(96, 32), dim3(256), 0, stream>>>(W, wthi, wtlo);

  const int NC = L_DIM / LC;
  for (int ci = 0; ci < NC; ++ci) {
    const int t0 = ci * LC;
    const float* xc = x + (size_t)t0 * B_DIM * D_DIM;
    const int nfl4 = LC * B_DIM * D_DIM / 4;
    prep_x<<<dim3(nfl4 / 256), dim3(256), 0, stream>>>(xc, xhi, xlo);
    gemm_kernel<<<dim3(24, LC * B_DIM / 128), dim3(256), 0, stream>>>(
        xhi, xlo, wthi, wtlo, u);
    const float* cin = (ci == 0) ? c0 : c_state;
    float* fdst = (ci == NC - 1) ? cell_out : c_state;
    scanA<<<dim3(BD / 256, NSUB), dim3(256), 0, stream>>>(
        u, bias, lens, Asum, Bsum, t0);
    scanB<<<dim3(BD / 256), dim3(256), 0, stream>>>(
        Asum, Bsum, cin, csin, c_state, fdst, NSUB);
    scanC<<<dim3(BD / 256, NSUB), dim3(256), 0, stream>>>(
        u, x, bias, csin, lens, out, t0);
  }
}